// Round 1
// 349.619 us; speedup vs baseline: 1.1851x; 1.1851x over previous
//
#include <hip/hip_runtime.h>
#include <math.h>

// ---------------------------------------------------------------------------
// REFT_Psi: B=65536 rows, DIM=64. 4 kernels (5 in fallback):
//  kA  : (grid 2, dir-split) mem-attn -> o_vec -> per-gate GRU constants;
//        G=pe@pe^T, v=pe@pi, pisq (block 0 only)
//  kB1 : fused ctx GEMM (K-split staged, 4 blocks/CU) -> logits+tpe GEMM
//        -> a0 diag-MFMA -> softmax/quadratic epilogue + emotion MLP ->
//        raw e to eout (ws copy if it fits, else O2)
//  kS  : reduce 1024 stress partials (fp64)
//  [kE : fallback only: O2 += 0.001*stress]
//  kC  : bi-GRU via MFMA; scalar stress folded as sc*rowsum(Wih_e) into cg2
//        (exact fp32 rank-1) so no per-row mean/wsum; async-staged m-tiles;
//        dir0 writes e_theta = e_raw + sc to O2 (fused path).
// ---------------------------------------------------------------------------

#define BATCH 65536
#define CTXD  384
#define NP    5
#define EPSV  1e-8f

typedef _Float16 h8 __attribute__((ext_vector_type(8)));
typedef _Float16 h4 __attribute__((ext_vector_type(4)));
typedef float f32x4 __attribute__((ext_vector_type(4)));
typedef float f4a __attribute__((ext_vector_type(4)));                 // 16B-aligned
typedef float f4u __attribute__((ext_vector_type(4), aligned(4)));     // 4B-aligned

// output offsets (floats)
#define O0 0
#define O1 4194304
#define O2 12582912
#define O3 16777216
#define O4 16842752
#define O5 16908288

// workspace offsets (floats)
#define WS_STRESS 0
#define WS_PART   256
#define NPART     1024
#define WS_GICF   1536
#define WS_GICR   1792
#define WS_G      2048   // 25 floats: pe@pe^T
#define WS_V      2080   // 5 floats: pe@prev_ideal
#define WS_PISQ   2088   // 1 float
#define WS_E      4096   // raw emotion e [B*64] (fused path only)

__device__ __forceinline__ float sigmoidf_(float x) {
  return 1.f / (1.f + __expf(-x));
}
__device__ __forceinline__ float tanhf_(float x) {
  float e2 = __expf(-2.f * x);
  return 2.f / (1.f + e2) - 1.f;
}
__device__ __forceinline__ h4 cvt4v(f4a v) {
  h4 o = {(_Float16)v[0], (_Float16)v[1], (_Float16)v[2], (_Float16)v[3]};
  return o;
}

// ---------------------------------------------------------------- kernel A
// grid 2: block 0 = fwd GIC + G/V/pisq, block 1 = rev GIC.
__global__ __launch_bounds__(256) void kA(
    const float* __restrict__ memory, const float* __restrict__ tw,
    const float* __restrict__ ipw, const float* __restrict__ ipb,
    const float* __restrict__ outw, const float* __restrict__ outb,
    const float* __restrict__ wihf, const float* __restrict__ bihf,
    const float* __restrict__ wihr, const float* __restrict__ bihr,
    const float* __restrict__ pe, const float* __restrict__ pi,
    float* __restrict__ ws)
{
  __shared__ __align__(16) float attn[16], mth[64], vv[64], ov[64];
  int t = threadIdx.x;
  int dir = blockIdx.x;
  if (t == 0) {
    float m = tw[0];
#pragma unroll
    for (int i = 1; i < 10; i++) m = fmaxf(m, tw[i]);
    float e[10]; float s = 0.f;
#pragma unroll
    for (int i = 0; i < 10; i++) { e[i] = __expf(tw[i] - m); s += e[i]; }
#pragma unroll
    for (int i = 0; i < 10; i++) attn[i] = e[i] / s;
  }
  if (dir == 0) {
    if (t < 25) {
      int l = t / 5, m2 = t - l * 5;
      const f4a* pa = (const f4a*)(pe + l * 64);
      const f4a* pb = (const f4a*)(pe + m2 * 64);
      float s = 0.f;
#pragma unroll
      for (int j = 0; j < 16; j++) {
        f4a a = pa[j], b = pb[j];
        s += a[0]*b[0] + a[1]*b[1] + a[2]*b[2] + a[3]*b[3];
      }
      ws[WS_G + t] = s;
    } else if (t >= 32 && t < 37) {
      int l = t - 32;
      const f4a* pa = (const f4a*)(pe + l * 64);
      const f4a* pb = (const f4a*)pi;
      float s = 0.f;
#pragma unroll
      for (int j = 0; j < 16; j++) {
        f4a a = pa[j], b = pb[j];
        s += a[0]*b[0] + a[1]*b[1] + a[2]*b[2] + a[3]*b[3];
      }
      ws[WS_V + l] = s;
    } else if (t == 40) {
      const f4a* pb = (const f4a*)pi;
      float s = 0.f;
#pragma unroll
      for (int j = 0; j < 16; j++) {
        f4a b = pb[j];
        s += b[0]*b[0] + b[1]*b[1] + b[2]*b[2] + b[3]*b[3];
      }
      ws[WS_PISQ] = s;
    }
  }
  __syncthreads();
  if (t < 64) {
    float a = 0.f;
#pragma unroll
    for (int m = 0; m < 10; m++) a += attn[m] * memory[m * 64 + t];
    mth[t] = a;
  }
  __syncthreads();
  if (t < 64) {
    const f4a* wr = (const f4a*)(ipw + (size_t)(128 + t) * 64);
    const f4a* mv = (const f4a*)mth;
    float a = ipb[128 + t];
#pragma unroll
    for (int j = 0; j < 16; j++) {
      f4a w = wr[j], o = mv[j];
      a += w[0]*o[0] + w[1]*o[1] + w[2]*o[2] + w[3]*o[3];
    }
    vv[t] = a;
  }
  __syncthreads();
  if (t < 64) {
    const f4a* wr = (const f4a*)(outw + (size_t)t * 64);
    const f4a* mv = (const f4a*)vv;
    float a = outb[t];
#pragma unroll
    for (int j = 0; j < 16; j++) {
      f4a w = wr[j], o = mv[j];
      a += w[0]*o[0] + w[1]*o[1] + w[2]*o[2] + w[3]*o[3];
    }
    ov[t] = a;
  }
  __syncthreads();
  if (t < 192) {
    const float* WIH = dir ? wihr : wihf;
    const float* BIH = dir ? bihr : bihf;
    float a = BIH[t];
    const f4a* ovv = (const f4a*)ov;
#pragma unroll
    for (int j = 0; j < 16; j++) {
      f4u w = *(const f4u*)(WIH + (size_t)t * 130 + j * 4);
      f4a o = ovv[j];
      a += w[0]*o[0] + w[1]*o[1] + w[2]*o[2] + w[3]*o[3];
    }
    ws[(dir ? WS_GICR : WS_GICF) + t] = a;
  }
}

// ---------------------------------------------------------------- kernel B1
// grid 1024, block 256 (4 waves), 64 rows/block.
// LDS: R-region 25600 (K-half ctile; later tth hi/lo; later mid+Lb+a0b+parts)
//      + cxout 9216 = 34816 B -> 4 blocks/CU.
__global__ __launch_bounds__(256, 4) void kB1(
    const float* __restrict__ theta, const float* __restrict__ context,
    const float* __restrict__ ctxw, const float* __restrict__ ctxb,
    const float* __restrict__ idealw, const float* __restrict__ idealb,
    const float* __restrict__ pe,
    const float* __restrict__ w1, const float* __restrict__ b1,
    const float* __restrict__ w2, const float* __restrict__ b2,
    const float* __restrict__ fw, const float* __restrict__ fb,
    float* __restrict__ dout, float* __restrict__ ws,
    float* __restrict__ eout)
{
  __shared__ __align__(16) char R[25600];
  __shared__ __align__(16) _Float16 cxout[64 * 72];
  _Float16* ctile = (_Float16*)R;                 // 64 x 200 halves (K-half)
  _Float16* tthhi = (_Float16*)R;                 //  9216: 64 x 72
  _Float16* tthlo = (_Float16*)(R + 9216);        //  9216: 64 x 72
  _Float16* mid   = (_Float16*)R;                 // 17408: 64 x 136 (after reg-load barrier)
  float*    Lb    = (float*)(R + 17408);          //  4352: 64 x 17
  float*    a0b   = (float*)(R + 21760);          //   256
  float*    parts = (float*)(R + 22016);          //   256

  int t = threadIdx.x, lane = t & 63, wv = t >> 6;
  int q = lane >> 4, c = lane & 15;
  int Rbase = blockIdx.x << 6;

  f32x4 acc[4];
#pragma unroll
  for (int mt = 0; mt < 4; mt++) acc[mt] = (f32x4)(0.f);
  float cbv = ctxb[wv * 16 + c];

  // ---- P0/P1: K-split ctx GEMM (two 64x192 halves through one buffer) ----
#pragma unroll
  for (int h = 0; h < 2; ++h) {
    if (h) __syncthreads();   // all reads of previous half done
    {
      const f4a* src = (const f4a*)context;
      f4a r0, r1, r2, r3, r4, r5, r6, r7, r8, r9, r10, r11;
#define CLD(j, rj) { int idx = t + (j) * 256; int row = idx / 48, pos = idx - row * 48; \
      rj = src[(size_t)(Rbase + row) * 96 + (size_t)h * 48 + pos]; }
#define CST(j, rj) { int idx = t + (j) * 256; int row = idx / 48, pos = idx - row * 48; \
      *(h4*)&ctile[row * 200 + pos * 4] = cvt4v(rj); }
      CLD(0, r0)  CLD(1, r1)  CLD(2, r2)  CLD(3, r3)
      CLD(4, r4)  CLD(5, r5)  CLD(6, r6)  CLD(7, r7)
      CLD(8, r8)  CLD(9, r9)  CLD(10, r10) CLD(11, r11)
      CST(0, r0)  CST(1, r1)  CST(2, r2)  CST(3, r3)
      CST(4, r4)  CST(5, r5)  CST(6, r6)  CST(7, r7)
      CST(8, r8)  CST(9, r9)  CST(10, r10) CST(11, r11)
#undef CLD
#undef CST
    }
    h8 bf[6];
    {
      const float* wp = ctxw + (size_t)(wv * 16 + c) * CTXD + h * 192 + q * 8;
#pragma unroll
      for (int ks = 0; ks < 6; ks++) {
        f4a u0 = *(const f4a*)(wp + ks * 32);
        f4a u1 = *(const f4a*)(wp + ks * 32 + 4);
        h8 b = {(_Float16)u0[0], (_Float16)u0[1], (_Float16)u0[2], (_Float16)u0[3],
                (_Float16)u1[0], (_Float16)u1[1], (_Float16)u1[2], (_Float16)u1[3]};
        bf[ks] = b;
      }
    }
    __syncthreads();   // ctile staged
#pragma unroll
    for (int mt = 0; mt < 4; mt++) {
      const _Float16* ar = &ctile[(mt * 16 + c) * 200 + q * 8];
#pragma unroll
      for (int ks = 0; ks < 6; ks++)
        acc[mt] = __builtin_amdgcn_mfma_f32_16x16x32_f16(*(const h8*)(ar + ks * 32),
                                                         bf[ks], acc[mt], 0, 0, 0);
    }
  }
  // cxout (fp16, bias folded)
#pragma unroll
  for (int mt = 0; mt < 4; mt++)
#pragma unroll
    for (int reg = 0; reg < 4; reg++)
      cxout[(mt * 16 + q * 4 + reg) * 72 + wv * 16 + c] = (_Float16)(acc[mt][reg] + cbv);
  __syncthreads();   // ctile dead; cxout stores done

  // ---- P2: stage theta hi/lo (split fp16), 4-deep batch ----
  {
    const f4a* ts = (const f4a*)(theta + (size_t)Rbase * 64);
    f4a s0 = ts[t], s1 = ts[t + 256], s2 = ts[t + 512], s3 = ts[t + 768];
#define TST(j, sj) { int idx = t + (j) * 256; int row = idx >> 4, pos = idx & 15; \
    h4 hi = cvt4v(sj); \
    f4a lo = {sj[0] - (float)hi[0], sj[1] - (float)hi[1], \
              sj[2] - (float)hi[2], sj[3] - (float)hi[3]}; \
    *(h4*)&tthhi[row * 72 + pos * 4] = hi; \
    *(h4*)&tthlo[row * 72 + pos * 4] = cvt4v(lo); }
    TST(0, s0) TST(1, s1) TST(2, s2) TST(3, s3)
#undef TST
  }
  // B-fragments for logits/tpe GEMM: rows 0-4 iw, 5-9 pe-hi, 10-14 pe-lo
  h8 bw[4];
#pragma unroll
  for (int ks = 0; ks < 4; ks++) {
#pragma unroll
    for (int j = 0; j < 8; j++) {
      int k = ks * 32 + q * 8 + j;
      float v = 0.f;
      if (c < 5) v = idealw[c * 128 + k];
      else if (c < 10) { if (k < 64) v = pe[(c - 5) * 64 + k]; }
      else if (c < 15) {
        if (k < 64) { float p = pe[(c - 10) * 64 + k]; v = p - (float)(_Float16)p; }
      }
      bw[ks][j] = (_Float16)v;
    }
  }
  __syncthreads();   // tth staged

  // ---- P3: load A-fragments (wave wv owns rows [16wv,16wv+16)) ----
  const _Float16* ahp = &tthhi[(16 * wv + c) * 72 + q * 8];
  const _Float16* alp = &tthlo[(16 * wv + c) * 72 + q * 8];
  const _Float16* acp = &cxout[(16 * wv + c) * 72 + q * 8];
  h8 ah0 = *(const h8*)(ahp);
  h8 ah1 = *(const h8*)(ahp + 32);
  h8 al0 = *(const h8*)(alp);
  h8 al1 = *(const h8*)(alp + 32);
  h8 ac0 = *(const h8*)(acp);
  h8 ac1 = *(const h8*)(acp + 32);
  __syncthreads();   // tth reads done -> R reusable as mid/Lb/a0b/parts

  // logits + tpe (K = [theta(64) | cx(64)], lo-pass on theta half)
  f32x4 Lacc = (f32x4)(0.f);
  Lacc = __builtin_amdgcn_mfma_f32_16x16x32_f16(ah0, bw[0], Lacc, 0, 0, 0);
  Lacc = __builtin_amdgcn_mfma_f32_16x16x32_f16(ah1, bw[1], Lacc, 0, 0, 0);
  Lacc = __builtin_amdgcn_mfma_f32_16x16x32_f16(ac0, bw[2], Lacc, 0, 0, 0);
  Lacc = __builtin_amdgcn_mfma_f32_16x16x32_f16(ac1, bw[3], Lacc, 0, 0, 0);
  Lacc = __builtin_amdgcn_mfma_f32_16x16x32_f16(al0, bw[0], Lacc, 0, 0, 0);
  Lacc = __builtin_amdgcn_mfma_f32_16x16x32_f16(al1, bw[1], Lacc, 0, 0, 0);
#pragma unroll
  for (int reg = 0; reg < 4; reg++)
    Lb[(16 * wv + q * 4 + reg) * 17 + c] = Lacc[reg];

  // a0 = ||theta||^2 via diag: hi.hi + 2 hi.lo
  {
    f32x4 hh = (f32x4)(0.f), hl = (f32x4)(0.f);
    hh = __builtin_amdgcn_mfma_f32_16x16x32_f16(ah0, ah0, hh, 0, 0, 0);
    hh = __builtin_amdgcn_mfma_f32_16x16x32_f16(ah1, ah1, hh, 0, 0, 0);
    hl = __builtin_amdgcn_mfma_f32_16x16x32_f16(ah0, al0, hl, 0, 0, 0);
    hl = __builtin_amdgcn_mfma_f32_16x16x32_f16(ah1, al1, hl, 0, 0, 0);
    if ((lane >> 4) == ((lane & 15) >> 2)) {
      int j = lane & 15;
      a0b[16 * wv + j] = hh[j & 3] + 2.f * hl[j & 3];
    }
  }

  // ---- emotion MLP layer 1 (reuses ah0/ah1) ----
#pragma unroll
  for (int tn = 0; tn < 8; tn++) {
    const float* wp = w1 + (size_t)(tn * 16 + c) * 64 + q * 8;
    f4a u0 = *(const f4a*)(wp);
    f4a u1 = *(const f4a*)(wp + 4);
    f4a u2 = *(const f4a*)(wp + 32);
    f4a u3 = *(const f4a*)(wp + 36);
    h8 b0 = {(_Float16)u0[0], (_Float16)u0[1], (_Float16)u0[2], (_Float16)u0[3],
             (_Float16)u1[0], (_Float16)u1[1], (_Float16)u1[2], (_Float16)u1[3]};
    h8 b1f = {(_Float16)u2[0], (_Float16)u2[1], (_Float16)u2[2], (_Float16)u2[3],
              (_Float16)u3[0], (_Float16)u3[1], (_Float16)u3[2], (_Float16)u3[3]};
    f32x4 a = (f32x4)(0.f);
    a = __builtin_amdgcn_mfma_f32_16x16x32_f16(ah0, b0, a, 0, 0, 0);
    a = __builtin_amdgcn_mfma_f32_16x16x32_f16(ah1, b1f, a, 0, 0, 0);
    float bv = b1[tn * 16 + c];
#pragma unroll
    for (int reg = 0; reg < 4; reg++)
      mid[(16 * wv + q * 4 + reg) * 136 + tn * 16 + c] = (_Float16)tanhf_(a[reg] + bv);
  }

  // ---- MLP layer 2 (wave-local mid) -> raw e ----
  {
    const _Float16* am = &mid[(16 * wv + c) * 136 + q * 8];
    h8 m0 = *(const h8*)(am);
    h8 m1 = *(const h8*)(am + 32);
    h8 m2 = *(const h8*)(am + 64);
    h8 m3 = *(const h8*)(am + 96);
#pragma unroll
    for (int tn = 0; tn < 4; tn++) {
      const float* wp = w2 + (size_t)(tn * 16 + c) * 128 + q * 8;
      f32x4 a = (f32x4)(0.f);
#pragma unroll
      for (int ks = 0; ks < 4; ks++) {
        f4a u0 = *(const f4a*)(wp + ks * 32);
        f4a u1 = *(const f4a*)(wp + ks * 32 + 4);
        h8 b = {(_Float16)u0[0], (_Float16)u0[1], (_Float16)u0[2], (_Float16)u0[3],
                (_Float16)u1[0], (_Float16)u1[1], (_Float16)u1[2], (_Float16)u1[3]};
        h8 av = (ks == 0) ? m0 : (ks == 1) ? m1 : (ks == 2) ? m2 : m3;
        a = __builtin_amdgcn_mfma_f32_16x16x32_f16(av, b, a, 0, 0, 0);
      }
      float bv = b2[tn * 16 + c];
#pragma unroll
      for (int reg = 0; reg < 4; reg++) {
        int row = Rbase + 16 * wv + q * 4 + reg;
        eout[((size_t)row << 6) + tn * 16 + c] = fmaxf(a[reg] + bv, 0.f);  // raw e
      }
    }
  }

  // ---- P4: per-row epilogue (lanes 0-15 of each wave own rows 16wv+lane) ----
  if (lane < 16) {
    int r = 16 * wv + lane;
    int row = Rbase + r;
    float L[NP], tpe[NP];
#pragma unroll
    for (int l = 0; l < NP; l++) {
      L[l]   = Lb[r * 17 + l] + idealb[l];
      tpe[l] = Lb[r * 17 + 5 + l] + Lb[r * 17 + 10 + l];
    }
    float mx = L[0];
#pragma unroll
    for (int l = 1; l < NP; l++) mx = fmaxf(mx, L[l]);
    float P[NP], s = 0.f;
#pragma unroll
    for (int l = 0; l < NP; l++) { P[l] = __expf(L[l] - mx); s += P[l]; }
    float inv = 1.f / s;
#pragma unroll
    for (int l = 0; l < NP; l++) P[l] *= inv;
#pragma unroll
    for (int l = 0; l < NP; l++) dout[O5 + (size_t)row * NP + l] = P[l];

    float a2 = 0.f, tipi = 0.f;
#pragma unroll
    for (int l = 0; l < NP; l++) {
      a2   += P[l] * tpe[l];
      tipi += P[l] * ws[WS_V + l];
    }
    float a1 = 0.f;
#pragma unroll
    for (int l = 0; l < NP; l++) {
      float pl = P[l];
#pragma unroll
      for (int m = 0; m < NP; m++) a1 += pl * P[m] * ws[WS_G + l * 5 + m];
    }
    float a0 = a0b[r];
    float a3 = fmaxf(a1 - 2.f * tipi + ws[WS_PISQ], 0.f);

    float na = sqrtf(a0), nb = sqrtf(a1);
    float qq = 1.f / ((na + EPSV) * (nb + EPSV));
    float num = a2 * qq;
    float den = fmaxf(na * nb * qq, EPSV);
    dout[O3 + row] = num / den;
    float fq = sqrtf(a3);
    float om = tanhf_(fq * fw[0] + fb[0]) * (1.f + 0.1f * __sinf(fq));
    dout[O4 + row] = om;

    parts[r] = a0 - 2.f * a2 + a1;
  }
  __syncthreads();
  if (t == 0) {
    float s = 0.f;
    for (int r = 0; r < 64; r++) s += parts[r];
    ws[WS_PART + blockIdx.x] = s;
  }
}

// ---------------------------------------------------------------- kernel S
__global__ __launch_bounds__(256) void kS(float* __restrict__ ws)
{
  __shared__ double sd[256];
  int t = threadIdx.x;
  double a = 0.0;
  for (int i = t; i < NPART; i += 256) a += (double)ws[WS_PART + i];
  sd[t] = a;
  __syncthreads();
  for (int off = 128; off > 0; off >>= 1) {
    if (t < off) sd[t] += sd[t + off];
    __syncthreads();
  }
  if (t == 0) ws[WS_STRESS] = (float)sd[0];
}

// ---------------------------------------------------------------- kernel E (fallback only)
__global__ __launch_bounds__(256) void kE(float* __restrict__ dout,
                                          const float* __restrict__ ws)
{
  float sc = 0.001f * ws[WS_STRESS];
  int i = blockIdx.x * 256 + threadIdx.x;
  float4* p = (float4*)(dout + O2);
  float4 v = p[i];
  v.x += sc; v.y += sc; v.z += sc; v.w += sc;
  p[i] = v;
}

// ---------------------------------------------------------------- kernel C
// MFMA bi-GRU. grid (256, 2): bx covers 256 rows (4 M-tiles of 64), by=dir.
// Stress is a scalar sc: fold sc*rowsum(Wih_e) into cg2 (exact fp32 rank-1),
// so ABuf holds raw e (small, fp16-safe) and no per-row reduction is needed.
// T14 async staging: issue next tile's e/h loads before compute, LDS-write late.
template <int FUSED>
__global__ __launch_bounds__(256) void kC(
    const float* __restrict__ theta, const float* __restrict__ hprev,
    const float* __restrict__ wihf, const float* __restrict__ whhf,
    const float* __restrict__ bhhf,
    const float* __restrict__ wihr, const float* __restrict__ whhr,
    const float* __restrict__ bhhr,
    const float* __restrict__ ws, const float* __restrict__ esrc,
    float* __restrict__ dout)
{
  __shared__ __align__(16) _Float16 WRZ[128 * 136];
  __shared__ __align__(16) _Float16 WN [64 * 72];
  __shared__ __align__(16) _Float16 WHN[64 * 72];
  __shared__ __align__(16) _Float16 ABuf[64 * 136];
  __shared__ float cg2[192], wre[192], wom[192], bhn[64];
  __shared__ float rLDS[64], oLDS[64];

  int t = threadIdx.x, lane = t & 63, wv = t >> 6;
  int q = lane >> 4, col = lane & 15;
  int dir = blockIdx.y;
  const float* WIH = dir ? wihr : wihf;
  const float* WHH = dir ? whhr : whhf;
  const float* BHH = dir ? bhhr : bhhf;
  const float* GIC = ws + (dir ? WS_GICR : WS_GICF);
  float sc = 0.001f * ws[WS_STRESS];

  // ---- weight staging, vectorized (f4u for the stride-130 WIH rows) ----
  for (int idx = t; idx < 128 * 32; idx += 256) {
    int n = idx >> 5, g = idx & 31;
    if (g < 16) {
      f4u v = *(const f4u*)(WIH + (size_t)n * 130 + 64 + g * 4);
      h4 o = {(_Float16)v[0], (_Float16)v[1], (_Float16)v[2], (_Float16)v[3]};
      *(h4*)&WRZ[n * 136 + g * 4] = o;
    } else {
      f4a v = *(const f4a*)(WHH + (size_t)n * 64 + (g - 16) * 4);
      *(h4*)&WRZ[n * 136 + 64 + (g - 16) * 4] = cvt4v(v);
    }
  }
  for (int idx = t; idx < 64 * 32; idx += 256) {
    int n = idx >> 5, g = idx & 31;
    if (g < 16) {
      f4u v = *(const f4u*)(WIH + (size_t)(128 + n) * 130 + 64 + g * 4);
      h4 o = {(_Float16)v[0], (_Float16)v[1], (_Float16)v[2], (_Float16)v[3]};
      *(h4*)&WN[n * 72 + g * 4] = o;
    } else {
      f4a v = *(const f4a*)(WHH + (size_t)(128 + n) * 64 + (g - 16) * 4);
      *(h4*)&WHN[n * 72 + (g - 16) * 4] = cvt4v(v);
    }
  }
  if (t < 192) {
    float s = 0.f;
#pragma unroll
    for (int j = 0; j < 16; j++) {
      f4u w = *(const f4u*)(WIH + (size_t)t * 130 + 64 + j * 4);
      s += w[0] + w[1] + w[2] + w[3];
    }
    wre[t] = WIH[t * 130 + 128];
    wom[t] = WIH[t * 130 + 129];
    cg2[t] = GIC[t] + (t < 128 ? BHH[t] : 0.f) + sc * s;
  }
  if (t < 64) bhn[t] = BHH[128 + t];

  int Mb0 = blockIdx.x << 8;
  f4a re0, re1, re2, re3, rh0, rh1, rh2, rh3;
  float rv_ = 0.f, ov_ = 0.f;

#define STAGE_LOAD(mb) do { \
    const f4a* e4 = (const f4a*)(esrc + ((size_t)(mb) << 6)); \
    const f4a* hp4 = (const f4a*)(hprev + (size_t)dir * (BATCH * 64) + ((size_t)(mb) << 6)); \
    re0 = e4[t]; re1 = e4[t + 256]; re2 = e4[t + 512]; re3 = e4[t + 768]; \
    rh0 = hp4[t]; rh1 = hp4[t + 256]; rh2 = hp4[t + 512]; rh3 = hp4[t + 768]; \
    if (t < 64) { rv_ = dout[O3 + (mb) + t]; ov_ = dout[O4 + (mb) + t]; } \
  } while (0)

#define ST1(j, rej, rhj, mb) do { \
    int idx = t + (j) * 256; int row = idx >> 4, p4 = idx & 15; \
    f4a ev = rej; \
    if (!FUSED) { ev[0] -= sc; ev[1] -= sc; ev[2] -= sc; ev[3] -= sc; } \
    *(h4*)&ABuf[row * 136 + p4 * 4] = cvt4v(ev); \
    *(h4*)&ABuf[row * 136 + 64 + p4 * 4] = cvt4v(rhj); \
    if (FUSED && dir == 0) { \
      f4a et = ev; et[0] += sc; et[1] += sc; et[2] += sc; et[3] += sc; \
      ((f4a*)(dout + O2))[((size_t)(mb) << 4) + idx] = et; \
    } \
  } while (0)

#define STAGE_WRITE(mb) do { \
    ST1(0, re0, rh0, mb); ST1(1, re1, rh1, mb); \
    ST1(2, re2, rh2, mb); ST1(3, re3, rh3, mb); \
    if (t < 64) { rLDS[t] = rv_; oLDS[t] = ov_; } \
  } while (0)

  STAGE_LOAD(Mb0);
  STAGE_WRITE(Mb0);

  for (int m = 0; m < 4; m++) {
    int Mbase = Mb0 + (m << 6);
    __syncthreads();                    // ABuf(m) + (m==0: weights) visible
    if (m < 3) STAGE_LOAD(Mbase + 64);  // prefetch next tile (regs only)

    const _Float16* arow = &ABuf[(16 * wv + col) * 136 + q * 8];
    h8 a0 = *(const h8*)(arow);
    h8 a1 = *(const h8*)(arow + 32);
    h8 a2 = *(const h8*)(arow + 64);
    h8 a3 = *(const h8*)(arow + 96);

    f32x4 accR[4], accZ[4], accN[4], accH[4];
#pragma unroll
    for (int td = 0; td < 4; td++) {
      accR[td] = (f32x4)(0.f); accZ[td] = (f32x4)(0.f);
      accN[td] = (f32x4)(0.f); accH[td] = (f32x4)(0.f);
    }
#pragma unroll
    for (int td = 0; td < 4; td++) {
      const _Float16* br = &WRZ[(td * 16 + col) * 136 + q * 8];
      accR[td] = __builtin_amdgcn_mfma_f32_16x16x32_f16(a0, *(const h8*)(br),      accR[td], 0, 0, 0);
      accR[td] = __builtin_amdgcn_mfma_f32_16x16x32_f16(a1, *(const h8*)(br + 32), accR[td], 0, 0, 0);
      accR[td] = __builtin_amdgcn_mfma_f32_16x16x32_f16(a2, *(const h8*)(br + 64), accR[td], 0, 0, 0);
      accR[td] = __builtin_amdgcn_mfma_f32_16x16x32_f16(a3, *(const h8*)(br + 96), accR[td], 0, 0, 0);
      const _Float16* bz = &WRZ[(64 + td * 16 + col) * 136 + q * 8];
      accZ[td] = __builtin_amdgcn_mfma_f32_16x16x32_f16(a0, *(const h8*)(bz),      accZ[td], 0, 0, 0);
      accZ[td] = __builtin_amdgcn_mfma_f32_16x16x32_f16(a1, *(const h8*)(bz + 32), accZ[td], 0, 0, 0);
      accZ[td] = __builtin_amdgcn_mfma_f32_16x16x32_f16(a2, *(const h8*)(bz + 64), accZ[td], 0, 0, 0);
      accZ[td] = __builtin_amdgcn_mfma_f32_16x16x32_f16(a3, *(const h8*)(bz + 96), accZ[td], 0, 0, 0);
      const _Float16* bn = &WN[(td * 16 + col) * 72 + q * 8];
      accN[td] = __builtin_amdgcn_mfma_f32_16x16x32_f16(a0, *(const h8*)(bn),      accN[td], 0, 0, 0);
      accN[td] = __builtin_amdgcn_mfma_f32_16x16x32_f16(a1, *(const h8*)(bn + 32), accN[td], 0, 0, 0);
      const _Float16* bh = &WHN[(td * 16 + col) * 72 + q * 8];
      accH[td] = __builtin_amdgcn_mfma_f32_16x16x32_f16(a2, *(const h8*)(bh),      accH[td], 0, 0, 0);
      accH[td] = __builtin_amdgcn_mfma_f32_16x16x32_f16(a3, *(const h8*)(bh + 32), accH[td], 0, 0, 0);
    }

#pragma unroll
    for (int reg = 0; reg < 4; reg++) {
      int lr  = 16 * wv + q * 4 + reg;
      int row = Mbase + lr;
      float rv = rLDS[lr], ovv = oLDS[lr];
#pragma unroll
      for (int td = 0; td < 4; td++) {
        int d = td * 16 + col;
        float hv = (float)ABuf[lr * 136 + 64 + d];
        float A0 = accR[td][reg] + cg2[d]       + rv * wre[d]       + ovv * wom[d];
        float A1 = accZ[td][reg] + cg2[64 + d]  + rv * wre[64 + d]  + ovv * wom[64 + d];
        float AN = accN[td][reg] + cg2[128 + d] + rv * wre[128 + d] + ovv * wom[128 + d];
        float AH = accH[td][reg] + bhn[d];
        float r  = sigmoidf_(A0);
        float z  = sigmoidf_(A1);
        float nn = tanhf_(AN + r * AH);
        float hf = (1.f - z) * nn + z * hv;
        dout[O1 + (size_t)dir * (BATCH * 64) + ((size_t)row << 6) + d] = hf;
        if (dir == 0) {
          dout[((size_t)row << 6) + d] = 0.3f * theta[((size_t)row << 6) + d] + 0.7f * hf;
        }
      }
    }
    __syncthreads();                    // all reads of ABuf(m)/rLDS/oLDS done
    if (m < 3) STAGE_WRITE(Mbase + 64);
  }
#undef STAGE_LOAD
#undef STAGE_WRITE
#undef ST1
}

// ---------------------------------------------------------------- launch
extern "C" void kernel_launch(void* const* d_in, const int* in_sizes, int n_in,
                              void* d_out, int out_size, void* d_ws, size_t ws_size,
                              hipStream_t stream)
{
  const float* theta   = (const float*)d_in[0];
  const float* context = (const float*)d_in[1];
  const float* h_prev  = (const float*)d_in[2];
  const float* memory  = (const float*)d_in[3];
  const float* tw      = (const float*)d_in[4];
  const float* ipw     = (const float*)d_in[5];
  const float* ipb     = (const float*)d_in[6];
  const float* outw    = (const float*)d_in[7];
  const float* outb    = (const float*)d_in[8];
  const float* ew1     = (const float*)d_in[9];
  const float* eb1     = (const float*)d_in[10];
  const float* ew2     = (const float*)d_in[11];
  const float* eb2     = (const float*)d_in[12];
  const float* pe      = (const float*)d_in[13];
  const float* cw      = (const float*)d_in[14];
  const float* cb      = (const float*)d_in[15];
  const float* iw      = (const float*)d_in[16];
  const float* ib      = (const float*)d_in[17];
  const float* wihf    = (const float*)d_in[18];
  const float* whhf    = (const float*)d_in[19];
  const float* bihf    = (const float*)d_in[20];
  const float* bhhf    = (const float*)d_in[21];
  const float* wihr    = (const float*)d_in[22];
  const float* whhr    = (const float*)d_in[23];
  const float* bihr    = (const float*)d_in[24];
  const float* bhhr    = (const float*)d_in[25];
  const float* fw      = (const float*)d_in[26];
  const float* fb      = (const float*)d_in[27];
  const float* pi      = (const float*)d_in[28];
  float* dout = (float*)d_out;
  float* ws   = (float*)d_ws;

  bool fused = ws_size >= ((size_t)WS_E + (size_t)BATCH * 64) * sizeof(float);
  float* eout = fused ? (ws + WS_E) : (dout + O2);

  kA<<<2, 256, 0, stream>>>(memory, tw, ipw, ipb, outw, outb, wihf, bihf,
                            wihr, bihr, pe, pi, ws);
  kB1<<<1024, 256, 0, stream>>>(theta, context, cw, cb, iw, ib, pe,
                                ew1, eb1, ew2, eb2, fw, fb, dout, ws, eout);
  kS<<<1, 256, 0, stream>>>(ws);
  if (fused) {
    kC<1><<<dim3(256, 2, 1), 256, 0, stream>>>(theta, h_prev, wihf, whhf, bhhf,
                                               wihr, whhr, bhhr, ws, ws + WS_E, dout);
  } else {
    kE<<<4096, 256, 0, stream>>>(dout, ws);
    kC<0><<<dim3(256, 2, 1), 256, 0, stream>>>(theta, h_prev, wihf, whhf, bhhf,
                                               wihr, whhr, bhhr, ws, dout + O2, dout);
  }
}

// Round 2
// 341.667 us; speedup vs baseline: 1.2127x; 1.0233x over previous
//
#include <hip/hip_runtime.h>
#include <math.h>

// ---------------------------------------------------------------------------
// REFT_Psi: B=65536 rows, DIM=64. 3 kernels (4 in fallback):
//  kA  : (grid 2, dir-split) mem-attn -> o_vec -> per-gate GRU constants;
//        G=pe@pe^T, v=pe@pi, pisq (block 0 only); zeroes WS_STRESS.
//  kB1 : fused ctx GEMM (4 K-quarters staged fp32 via global_load_lds,
//        cvt-on-read, 4 blocks/CU) -> logits+tpe GEMM -> a0 diag-MFMA ->
//        softmax/quadratic epilogue + emotion MLP -> raw e to eout;
//        block partial stress atomicAdd'd into WS_STRESS (kS removed).
//  [kE : fallback only: O2 += 0.001*stress]
//  kC  : bi-GRU via MFMA; scalar stress folded as sc*rowsum(Wih_e) into cg2;
//        depth-2 async staging (reg sets a/b); dir0 writes e_theta to O2.
// ---------------------------------------------------------------------------

#define BATCH 65536
#define CTXD  384
#define NP    5
#define EPSV  1e-8f

typedef _Float16 h8 __attribute__((ext_vector_type(8)));
typedef _Float16 h4 __attribute__((ext_vector_type(4)));
typedef float f32x4 __attribute__((ext_vector_type(4)));
typedef float f4a __attribute__((ext_vector_type(4)));                 // 16B-aligned
typedef float f4u __attribute__((ext_vector_type(4), aligned(4)));     // 4B-aligned

// output offsets (floats)
#define O0 0
#define O1 4194304
#define O2 12582912
#define O3 16777216
#define O4 16842752
#define O5 16908288

// workspace offsets (floats)
#define WS_STRESS 0
#define WS_GICF   1536
#define WS_GICR   1792
#define WS_G      2048   // 25 floats: pe@pe^T
#define WS_V      2080   // 5 floats: pe@prev_ideal
#define WS_PISQ   2088   // 1 float
#define WS_E      4096   // raw emotion e [B*64] (fused path only)

__device__ __forceinline__ float sigmoidf_(float x) {
  return 1.f / (1.f + __expf(-x));
}
__device__ __forceinline__ float tanhf_(float x) {
  float e2 = __expf(-2.f * x);
  return 2.f / (1.f + e2) - 1.f;
}
__device__ __forceinline__ h4 cvt4v(f4a v) {
  h4 o = {(_Float16)v[0], (_Float16)v[1], (_Float16)v[2], (_Float16)v[3]};
  return o;
}

// async global->LDS, 16 B per lane; lds ptr must be wave-uniform base.
typedef __attribute__((address_space(1))) const void gas_t;
typedef __attribute__((address_space(3))) void las_t;
__device__ __forceinline__ void gload_lds16(const float* g, float* l) {
  __builtin_amdgcn_global_load_lds((gas_t*)g, (las_t*)l, 16, 0, 0);
}

// ---------------------------------------------------------------- kernel A
// grid 2: block 0 = fwd GIC + G/V/pisq + stress zero, block 1 = rev GIC.
__global__ __launch_bounds__(256) void kA(
    const float* __restrict__ memory, const float* __restrict__ tw,
    const float* __restrict__ ipw, const float* __restrict__ ipb,
    const float* __restrict__ outw, const float* __restrict__ outb,
    const float* __restrict__ wihf, const float* __restrict__ bihf,
    const float* __restrict__ wihr, const float* __restrict__ bihr,
    const float* __restrict__ pe, const float* __restrict__ pi,
    float* __restrict__ ws)
{
  __shared__ __align__(16) float attn[16], mth[64], vv[64], ov[64];
  int t = threadIdx.x;
  int dir = blockIdx.x;
  if (t == 0) {
    float m = tw[0];
#pragma unroll
    for (int i = 1; i < 10; i++) m = fmaxf(m, tw[i]);
    float e[10]; float s = 0.f;
#pragma unroll
    for (int i = 0; i < 10; i++) { e[i] = __expf(tw[i] - m); s += e[i]; }
#pragma unroll
    for (int i = 0; i < 10; i++) attn[i] = e[i] / s;
  }
  if (dir == 0) {
    if (t < 25) {
      int l = t / 5, m2 = t - l * 5;
      const f4a* pa = (const f4a*)(pe + l * 64);
      const f4a* pb = (const f4a*)(pe + m2 * 64);
      float s = 0.f;
#pragma unroll
      for (int j = 0; j < 16; j++) {
        f4a a = pa[j], b = pb[j];
        s += a[0]*b[0] + a[1]*b[1] + a[2]*b[2] + a[3]*b[3];
      }
      ws[WS_G + t] = s;
    } else if (t >= 32 && t < 37) {
      int l = t - 32;
      const f4a* pa = (const f4a*)(pe + l * 64);
      const f4a* pb = (const f4a*)pi;
      float s = 0.f;
#pragma unroll
      for (int j = 0; j < 16; j++) {
        f4a a = pa[j], b = pb[j];
        s += a[0]*b[0] + a[1]*b[1] + a[2]*b[2] + a[3]*b[3];
      }
      ws[WS_V + l] = s;
    } else if (t == 40) {
      const f4a* pb = (const f4a*)pi;
      float s = 0.f;
#pragma unroll
      for (int j = 0; j < 16; j++) {
        f4a b = pb[j];
        s += b[0]*b[0] + b[1]*b[1] + b[2]*b[2] + b[3]*b[3];
      }
      ws[WS_PISQ] = s;
    } else if (t == 41) {
      ws[WS_STRESS] = 0.f;    // kB1 accumulates atomically
    }
  }
  __syncthreads();
  if (t < 64) {
    float a = 0.f;
#pragma unroll
    for (int m = 0; m < 10; m++) a += attn[m] * memory[m * 64 + t];
    mth[t] = a;
  }
  __syncthreads();
  if (t < 64) {
    const f4a* wr = (const f4a*)(ipw + (size_t)(128 + t) * 64);
    const f4a* mv = (const f4a*)mth;
    float a = ipb[128 + t];
#pragma unroll
    for (int j = 0; j < 16; j++) {
      f4a w = wr[j], o = mv[j];
      a += w[0]*o[0] + w[1]*o[1] + w[2]*o[2] + w[3]*o[3];
    }
    vv[t] = a;
  }
  __syncthreads();
  if (t < 64) {
    const f4a* wr = (const f4a*)(outw + (size_t)t * 64);
    const f4a* mv = (const f4a*)vv;
    float a = outb[t];
#pragma unroll
    for (int j = 0; j < 16; j++) {
      f4a w = wr[j], o = mv[j];
      a += w[0]*o[0] + w[1]*o[1] + w[2]*o[2] + w[3]*o[3];
    }
    ov[t] = a;
  }
  __syncthreads();
  if (t < 192) {
    const float* WIH = dir ? wihr : wihf;
    const float* BIH = dir ? bihr : bihf;
    float a = BIH[t];
    const f4a* ovv = (const f4a*)ov;
#pragma unroll
    for (int j = 0; j < 16; j++) {
      f4u w = *(const f4u*)(WIH + (size_t)t * 130 + j * 4);
      f4a o = ovv[j];
      a += w[0]*o[0] + w[1]*o[1] + w[2]*o[2] + w[3]*o[3];
    }
    ws[(dir ? WS_GICR : WS_GICF) + t] = a;
  }
}

// ---------------------------------------------------------------- kernel B1
// grid 1024, block 256 (4 waves), 64 rows/block.
// LDS: R-region 25600 (fp32 ctx quarter [64][100]; later tth hi/lo; later
//      mid+Lb+a0b+parts) + cxout 9216 = 34816 B -> 4 blocks/CU.
__global__ __launch_bounds__(256, 4) void kB1(
    const float* __restrict__ theta, const float* __restrict__ context,
    const float* __restrict__ ctxw, const float* __restrict__ ctxb,
    const float* __restrict__ idealw, const float* __restrict__ idealb,
    const float* __restrict__ pe,
    const float* __restrict__ w1, const float* __restrict__ b1,
    const float* __restrict__ w2, const float* __restrict__ b2,
    const float* __restrict__ fw, const float* __restrict__ fb,
    float* __restrict__ dout, float* __restrict__ ws,
    float* __restrict__ eout)
{
  __shared__ __align__(16) char R[25600];
  __shared__ __align__(16) _Float16 cxout[64 * 72];
  float*    cf    = (float*)R;                    // 25600: 64 x 100 fp32 (quarter)
  _Float16* tthhi = (_Float16*)R;                 //  9216: 64 x 72
  _Float16* tthlo = (_Float16*)(R + 9216);        //  9216: 64 x 72
  _Float16* mid   = (_Float16*)R;                 // 17408: 64 x 136 (after reg-load barrier)
  float*    Lb    = (float*)(R + 17408);          //  4352: 64 x 17
  float*    a0b   = (float*)(R + 21760);          //   256
  float*    parts = (float*)(R + 22016);          //   256

  int t = threadIdx.x, lane = t & 63, wv = t >> 6;
  int q = lane >> 4, c = lane & 15;
  int Rbase = blockIdx.x << 6;

  // hoist theta loads (consumed at P2) so their latency hides under P0/P1
  const f4a* ts = (const f4a*)(theta + (size_t)Rbase * 64);
  f4a th0 = ts[t], th1 = ts[t + 256], th2 = ts[t + 512], th3 = ts[t + 768];

  f32x4 acc[4];
#pragma unroll
  for (int mt = 0; mt < 4; mt++) acc[mt] = (f32x4)(0.f);
  float cbv = ctxb[wv * 16 + c];

  // ---- P0/P1: ctx GEMM, 4 K-quarters (96 each) staged fp32 via
  //      global_load_lds (fire-and-forget; whole quarter in flight) ----
#pragma unroll 1
  for (int qtr = 0; qtr < 4; ++qtr) {
    if (qtr) __syncthreads();   // prior quarter's ds_reads done
    {
      const float* srcq = context + qtr * 96;
      // 1600 float4 LDS slots ([64][25]); slot idx -> row=idx/25, pos=idx%25;
      // pos 24 is pad (clamped source, never read back)
#pragma unroll
      for (int j = 0; j < 6; ++j) {
        int idx = t + j * 256;
        int row = idx / 25, pos = idx - row * 25;
        if (pos > 23) pos = 23;
        const float* g = srcq + (size_t)(Rbase + row) * CTXD + pos * 4;
        gload_lds16(g, cf + (size_t)(j * 256 + wv * 64) * 4);
      }
      if (wv == 0) {
        int idx = lane + 1536;
        int row = idx / 25, pos = idx - row * 25;
        if (pos > 23) pos = 23;
        const float* g = srcq + (size_t)(Rbase + row) * CTXD + pos * 4;
        gload_lds16(g, cf + (size_t)1536 * 4);
      }
    }
    // B fragments for this quarter (overlap with lds loads)
    h8 bq[3];
    {
      const float* wp = ctxw + (size_t)(wv * 16 + c) * CTXD + qtr * 96 + q * 8;
#pragma unroll
      for (int ks = 0; ks < 3; ++ks) {
        f4a u0 = *(const f4a*)(wp + ks * 32);
        f4a u1 = *(const f4a*)(wp + ks * 32 + 4);
        h8 b = {(_Float16)u0[0], (_Float16)u0[1], (_Float16)u0[2], (_Float16)u0[3],
                (_Float16)u1[0], (_Float16)u1[1], (_Float16)u1[2], (_Float16)u1[3]};
        bq[ks] = b;
      }
    }
    __syncthreads();   // drains vmcnt -> quarter visible
#pragma unroll
    for (int mt = 0; mt < 4; ++mt) {
      const float* ap = cf + (mt * 16 + c) * 100 + q * 8;
#pragma unroll
      for (int ks = 0; ks < 3; ++ks) {
        f4a x0 = *(const f4a*)(ap + ks * 32);
        f4a x1 = *(const f4a*)(ap + ks * 32 + 4);
        h8 av = {(_Float16)x0[0], (_Float16)x0[1], (_Float16)x0[2], (_Float16)x0[3],
                 (_Float16)x1[0], (_Float16)x1[1], (_Float16)x1[2], (_Float16)x1[3]};
        acc[mt] = __builtin_amdgcn_mfma_f32_16x16x32_f16(av, bq[ks], acc[mt], 0, 0, 0);
      }
    }
  }
  // cxout (fp16, bias folded)
#pragma unroll
  for (int mt = 0; mt < 4; mt++)
#pragma unroll
    for (int reg = 0; reg < 4; reg++)
      cxout[(mt * 16 + q * 4 + reg) * 72 + wv * 16 + c] = (_Float16)(acc[mt][reg] + cbv);
  __syncthreads();   // cf dead; cxout stores done

  // ---- P2: stage theta hi/lo (split fp16) from hoisted regs ----
  {
#define TST(j, sj) { int idx = t + (j) * 256; int row = idx >> 4, pos = idx & 15; \
    h4 hi = cvt4v(sj); \
    f4a lo = {sj[0] - (float)hi[0], sj[1] - (float)hi[1], \
              sj[2] - (float)hi[2], sj[3] - (float)hi[3]}; \
    *(h4*)&tthhi[row * 72 + pos * 4] = hi; \
    *(h4*)&tthlo[row * 72 + pos * 4] = cvt4v(lo); }
    TST(0, th0) TST(1, th1) TST(2, th2) TST(3, th3)
#undef TST
  }
  // B-fragments for logits/tpe GEMM: rows 0-4 iw, 5-9 pe-hi, 10-14 pe-lo
  h8 bw[4];
#pragma unroll
  for (int ks = 0; ks < 4; ks++) {
#pragma unroll
    for (int j = 0; j < 8; j++) {
      int k = ks * 32 + q * 8 + j;
      float v = 0.f;
      if (c < 5) v = idealw[c * 128 + k];
      else if (c < 10) { if (k < 64) v = pe[(c - 5) * 64 + k]; }
      else if (c < 15) {
        if (k < 64) { float p = pe[(c - 10) * 64 + k]; v = p - (float)(_Float16)p; }
      }
      bw[ks][j] = (_Float16)v;
    }
  }
  __syncthreads();   // tth staged

  // ---- P3: load A-fragments (wave wv owns rows [16wv,16wv+16)) ----
  const _Float16* ahp = &tthhi[(16 * wv + c) * 72 + q * 8];
  const _Float16* alp = &tthlo[(16 * wv + c) * 72 + q * 8];
  const _Float16* acp = &cxout[(16 * wv + c) * 72 + q * 8];
  h8 ah0 = *(const h8*)(ahp);
  h8 ah1 = *(const h8*)(ahp + 32);
  h8 al0 = *(const h8*)(alp);
  h8 al1 = *(const h8*)(alp + 32);
  h8 ac0 = *(const h8*)(acp);
  h8 ac1 = *(const h8*)(acp + 32);
  __syncthreads();   // tth reads done -> R reusable as mid/Lb/a0b/parts

  // logits + tpe (K = [theta(64) | cx(64)], lo-pass on theta half)
  f32x4 Lacc = (f32x4)(0.f);
  Lacc = __builtin_amdgcn_mfma_f32_16x16x32_f16(ah0, bw[0], Lacc, 0, 0, 0);
  Lacc = __builtin_amdgcn_mfma_f32_16x16x32_f16(ah1, bw[1], Lacc, 0, 0, 0);
  Lacc = __builtin_amdgcn_mfma_f32_16x16x32_f16(ac0, bw[2], Lacc, 0, 0, 0);
  Lacc = __builtin_amdgcn_mfma_f32_16x16x32_f16(ac1, bw[3], Lacc, 0, 0, 0);
  Lacc = __builtin_amdgcn_mfma_f32_16x16x32_f16(al0, bw[0], Lacc, 0, 0, 0);
  Lacc = __builtin_amdgcn_mfma_f32_16x16x32_f16(al1, bw[1], Lacc, 0, 0, 0);
#pragma unroll
  for (int reg = 0; reg < 4; reg++)
    Lb[(16 * wv + q * 4 + reg) * 17 + c] = Lacc[reg];

  // a0 = ||theta||^2 via diag: hi.hi + 2 hi.lo
  {
    f32x4 hh = (f32x4)(0.f), hl = (f32x4)(0.f);
    hh = __builtin_amdgcn_mfma_f32_16x16x32_f16(ah0, ah0, hh, 0, 0, 0);
    hh = __builtin_amdgcn_mfma_f32_16x16x32_f16(ah1, ah1, hh, 0, 0, 0);
    hl = __builtin_amdgcn_mfma_f32_16x16x32_f16(ah0, al0, hl, 0, 0, 0);
    hl = __builtin_amdgcn_mfma_f32_16x16x32_f16(ah1, al1, hl, 0, 0, 0);
    if ((lane >> 4) == ((lane & 15) >> 2)) {
      int j = lane & 15;
      a0b[16 * wv + j] = hh[j & 3] + 2.f * hl[j & 3];
    }
  }

  // ---- emotion MLP layer 1 (reuses ah0/ah1) ----
#pragma unroll
  for (int tn = 0; tn < 8; tn++) {
    const float* wp = w1 + (size_t)(tn * 16 + c) * 64 + q * 8;
    f4a u0 = *(const f4a*)(wp);
    f4a u1 = *(const f4a*)(wp + 4);
    f4a u2 = *(const f4a*)(wp + 32);
    f4a u3 = *(const f4a*)(wp + 36);
    h8 b0 = {(_Float16)u0[0], (_Float16)u0[1], (_Float16)u0[2], (_Float16)u0[3],
             (_Float16)u1[0], (_Float16)u1[1], (_Float16)u1[2], (_Float16)u1[3]};
    h8 b1f = {(_Float16)u2[0], (_Float16)u2[1], (_Float16)u2[2], (_Float16)u2[3],
              (_Float16)u3[0], (_Float16)u3[1], (_Float16)u3[2], (_Float16)u3[3]};
    f32x4 a = (f32x4)(0.f);
    a = __builtin_amdgcn_mfma_f32_16x16x32_f16(ah0, b0, a, 0, 0, 0);
    a = __builtin_amdgcn_mfma_f32_16x16x32_f16(ah1, b1f, a, 0, 0, 0);
    float bv = b1[tn * 16 + c];
#pragma unroll
    for (int reg = 0; reg < 4; reg++)
      mid[(16 * wv + q * 4 + reg) * 136 + tn * 16 + c] = (_Float16)tanhf_(a[reg] + bv);
  }

  // ---- MLP layer 2 (wave-local mid) -> raw e ----
  {
    const _Float16* am = &mid[(16 * wv + c) * 136 + q * 8];
    h8 m0 = *(const h8*)(am);
    h8 m1 = *(const h8*)(am + 32);
    h8 m2 = *(const h8*)(am + 64);
    h8 m3 = *(const h8*)(am + 96);
#pragma unroll
    for (int tn = 0; tn < 4; tn++) {
      const float* wp = w2 + (size_t)(tn * 16 + c) * 128 + q * 8;
      f32x4 a = (f32x4)(0.f);
#pragma unroll
      for (int ks = 0; ks < 4; ks++) {
        f4a u0 = *(const f4a*)(wp + ks * 32);
        f4a u1 = *(const f4a*)(wp + ks * 32 + 4);
        h8 b = {(_Float16)u0[0], (_Float16)u0[1], (_Float16)u0[2], (_Float16)u0[3],
                (_Float16)u1[0], (_Float16)u1[1], (_Float16)u1[2], (_Float16)u1[3]};
        h8 av = (ks == 0) ? m0 : (ks == 1) ? m1 : (ks == 2) ? m2 : m3;
        a = __builtin_amdgcn_mfma_f32_16x16x32_f16(av, b, a, 0, 0, 0);
      }
      float bv = b2[tn * 16 + c];
#pragma unroll
      for (int reg = 0; reg < 4; reg++) {
        int row = Rbase + 16 * wv + q * 4 + reg;
        eout[((size_t)row << 6) + tn * 16 + c] = fmaxf(a[reg] + bv, 0.f);  // raw e
      }
    }
  }

  // ---- P4: per-row epilogue (lanes 0-15 of each wave own rows 16wv+lane) ----
  if (lane < 16) {
    int r = 16 * wv + lane;
    int row = Rbase + r;
    float L[NP], tpe[NP];
#pragma unroll
    for (int l = 0; l < NP; l++) {
      L[l]   = Lb[r * 17 + l] + idealb[l];
      tpe[l] = Lb[r * 17 + 5 + l] + Lb[r * 17 + 10 + l];
    }
    float mx = L[0];
#pragma unroll
    for (int l = 1; l < NP; l++) mx = fmaxf(mx, L[l]);
    float P[NP], s = 0.f;
#pragma unroll
    for (int l = 0; l < NP; l++) { P[l] = __expf(L[l] - mx); s += P[l]; }
    float inv = 1.f / s;
#pragma unroll
    for (int l = 0; l < NP; l++) P[l] *= inv;
#pragma unroll
    for (int l = 0; l < NP; l++) dout[O5 + (size_t)row * NP + l] = P[l];

    float a2 = 0.f, tipi = 0.f;
#pragma unroll
    for (int l = 0; l < NP; l++) {
      a2   += P[l] * tpe[l];
      tipi += P[l] * ws[WS_V + l];
    }
    float a1 = 0.f;
#pragma unroll
    for (int l = 0; l < NP; l++) {
      float pl = P[l];
#pragma unroll
      for (int m = 0; m < NP; m++) a1 += pl * P[m] * ws[WS_G + l * 5 + m];
    }
    float a0 = a0b[r];
    float a3 = fmaxf(a1 - 2.f * tipi + ws[WS_PISQ], 0.f);

    float na = sqrtf(a0), nb = sqrtf(a1);
    float qq = 1.f / ((na + EPSV) * (nb + EPSV));
    float num = a2 * qq;
    float den = fmaxf(na * nb * qq, EPSV);
    dout[O3 + row] = num / den;
    float fq = sqrtf(a3);
    float om = tanhf_(fq * fw[0] + fb[0]) * (1.f + 0.1f * __sinf(fq));
    dout[O4 + row] = om;

    parts[r] = a0 - 2.f * a2 + a1;
  }
  __syncthreads();
  if (t == 0) {
    float s = 0.f;
    for (int r = 0; r < 64; r++) s += parts[r];
    atomicAdd(&ws[WS_STRESS], s);   // WS_STRESS zeroed by kA (stream-prior)
  }
}

// ---------------------------------------------------------------- kernel E (fallback only)
__global__ __launch_bounds__(256) void kE(float* __restrict__ dout,
                                          const float* __restrict__ ws)
{
  float sc = 0.001f * ws[WS_STRESS];
  int i = blockIdx.x * 256 + threadIdx.x;
  float4* p = (float4*)(dout + O2);
  float4 v = p[i];
  v.x += sc; v.y += sc; v.z += sc; v.w += sc;
  p[i] = v;
}

// ---------------------------------------------------------------- kernel C
// MFMA bi-GRU. grid (256, 2): bx covers 256 rows (4 M-tiles of 64), by=dir.
// Stress is a scalar sc: fold sc*rowsum(Wih_e) into cg2 (exact fp32 rank-1).
// Depth-2 async staging: two named reg sets (a/b) so each tile's global
// loads are issued one full iteration ahead of their LDS write.
template <int FUSED>
__global__ __launch_bounds__(256) void kC(
    const float* __restrict__ theta, const float* __restrict__ hprev,
    const float* __restrict__ wihf, const float* __restrict__ whhf,
    const float* __restrict__ bhhf,
    const float* __restrict__ wihr, const float* __restrict__ whhr,
    const float* __restrict__ bhhr,
    const float* __restrict__ ws, const float* __restrict__ esrc,
    float* __restrict__ dout)
{
  __shared__ __align__(16) _Float16 WRZ[128 * 136];
  __shared__ __align__(16) _Float16 WN [64 * 72];
  __shared__ __align__(16) _Float16 WHN[64 * 72];
  __shared__ __align__(16) _Float16 ABuf[64 * 136];
  __shared__ float cg2[192], wre[192], wom[192], bhn[64];
  __shared__ float rLDS[64], oLDS[64];

  int t = threadIdx.x, lane = t & 63, wv = t >> 6;
  int q = lane >> 4, col = lane & 15;
  int dir = blockIdx.y;
  const float* WIH = dir ? wihr : wihf;
  const float* WHH = dir ? whhr : whhf;
  const float* BHH = dir ? bhhr : bhhf;
  const float* GIC = ws + (dir ? WS_GICR : WS_GICF);
  float sc = 0.001f * ws[WS_STRESS];

  // ---- weight staging, vectorized (f4u for the stride-130 WIH rows) ----
  for (int idx = t; idx < 128 * 32; idx += 256) {
    int n = idx >> 5, g = idx & 31;
    if (g < 16) {
      f4u v = *(const f4u*)(WIH + (size_t)n * 130 + 64 + g * 4);
      h4 o = {(_Float16)v[0], (_Float16)v[1], (_Float16)v[2], (_Float16)v[3]};
      *(h4*)&WRZ[n * 136 + g * 4] = o;
    } else {
      f4a v = *(const f4a*)(WHH + (size_t)n * 64 + (g - 16) * 4);
      *(h4*)&WRZ[n * 136 + 64 + (g - 16) * 4] = cvt4v(v);
    }
  }
  for (int idx = t; idx < 64 * 32; idx += 256) {
    int n = idx >> 5, g = idx & 31;
    if (g < 16) {
      f4u v = *(const f4u*)(WIH + (size_t)(128 + n) * 130 + 64 + g * 4);
      h4 o = {(_Float16)v[0], (_Float16)v[1], (_Float16)v[2], (_Float16)v[3]};
      *(h4*)&WN[n * 72 + g * 4] = o;
    } else {
      f4a v = *(const f4a*)(WHH + (size_t)(128 + n) * 64 + (g - 16) * 4);
      *(h4*)&WHN[n * 72 + (g - 16) * 4] = cvt4v(v);
    }
  }
  if (t < 192) {
    float s = 0.f;
#pragma unroll
    for (int j = 0; j < 16; j++) {
      f4u w = *(const f4u*)(WIH + (size_t)t * 130 + 64 + j * 4);
      s += w[0] + w[1] + w[2] + w[3];
    }
    wre[t] = WIH[t * 130 + 128];
    wom[t] = WIH[t * 130 + 129];
    cg2[t] = GIC[t] + (t < 128 ? BHH[t] : 0.f) + sc * s;
  }
  if (t < 64) bhn[t] = BHH[128 + t];

  int Mb0 = blockIdx.x << 8;
  f4a rea0, rea1, rea2, rea3, rha0, rha1, rha2, rha3;
  f4a reb0, reb1, reb2, reb3, rhb0, rhb1, rhb2, rhb3;
  float rva = 0.f, ova = 0.f, rvb = 0.f, ovb = 0.f;

#define STAGE_LOAD(S, mb) do { \
    const f4a* e4 = (const f4a*)(esrc + ((size_t)(mb) << 6)); \
    const f4a* hp4 = (const f4a*)(hprev + (size_t)dir * (BATCH * 64) + ((size_t)(mb) << 6)); \
    re##S##0 = e4[t]; re##S##1 = e4[t + 256]; re##S##2 = e4[t + 512]; re##S##3 = e4[t + 768]; \
    rh##S##0 = hp4[t]; rh##S##1 = hp4[t + 256]; rh##S##2 = hp4[t + 512]; rh##S##3 = hp4[t + 768]; \
    if (t < 64) { rv##S = dout[O3 + (mb) + t]; ov##S = dout[O4 + (mb) + t]; } \
  } while (0)

#define ST1(j, rej, rhj, mb) do { \
    int idx = t + (j) * 256; int row = idx >> 4, p4 = idx & 15; \
    f4a ev = rej; \
    if (!FUSED) { ev[0] -= sc; ev[1] -= sc; ev[2] -= sc; ev[3] -= sc; } \
    *(h4*)&ABuf[row * 136 + p4 * 4] = cvt4v(ev); \
    *(h4*)&ABuf[row * 136 + 64 + p4 * 4] = cvt4v(rhj); \
    if (FUSED && dir == 0) { \
      f4a et = ev; et[0] += sc; et[1] += sc; et[2] += sc; et[3] += sc; \
      ((f4a*)(dout + O2))[((size_t)(mb) << 4) + idx] = et; \
    } \
  } while (0)

#define STAGE_WRITE(S, mb) do { \
    ST1(0, re##S##0, rh##S##0, mb); ST1(1, re##S##1, rh##S##1, mb); \
    ST1(2, re##S##2, rh##S##2, mb); ST1(3, re##S##3, rh##S##3, mb); \
    if (t < 64) { rLDS[t] = rv##S; oLDS[t] = ov##S; } \
  } while (0)

  auto compute = [&](int Mbase) {
    const _Float16* arow = &ABuf[(16 * wv + col) * 136 + q * 8];
    h8 a0 = *(const h8*)(arow);
    h8 a1 = *(const h8*)(arow + 32);
    h8 a2 = *(const h8*)(arow + 64);
    h8 a3 = *(const h8*)(arow + 96);

    f32x4 accR[4], accZ[4], accN[4], accH[4];
#pragma unroll
    for (int td = 0; td < 4; td++) {
      accR[td] = (f32x4)(0.f); accZ[td] = (f32x4)(0.f);
      accN[td] = (f32x4)(0.f); accH[td] = (f32x4)(0.f);
    }
#pragma unroll
    for (int td = 0; td < 4; td++) {
      const _Float16* br = &WRZ[(td * 16 + col) * 136 + q * 8];
      accR[td] = __builtin_amdgcn_mfma_f32_16x16x32_f16(a0, *(const h8*)(br),      accR[td], 0, 0, 0);
      accR[td] = __builtin_amdgcn_mfma_f32_16x16x32_f16(a1, *(const h8*)(br + 32), accR[td], 0, 0, 0);
      accR[td] = __builtin_amdgcn_mfma_f32_16x16x32_f16(a2, *(const h8*)(br + 64), accR[td], 0, 0, 0);
      accR[td] = __builtin_amdgcn_mfma_f32_16x16x32_f16(a3, *(const h8*)(br + 96), accR[td], 0, 0, 0);
      const _Float16* bz = &WRZ[(64 + td * 16 + col) * 136 + q * 8];
      accZ[td] = __builtin_amdgcn_mfma_f32_16x16x32_f16(a0, *(const h8*)(bz),      accZ[td], 0, 0, 0);
      accZ[td] = __builtin_amdgcn_mfma_f32_16x16x32_f16(a1, *(const h8*)(bz + 32), accZ[td], 0, 0, 0);
      accZ[td] = __builtin_amdgcn_mfma_f32_16x16x32_f16(a2, *(const h8*)(bz + 64), accZ[td], 0, 0, 0);
      accZ[td] = __builtin_amdgcn_mfma_f32_16x16x32_f16(a3, *(const h8*)(bz + 96), accZ[td], 0, 0, 0);
      const _Float16* bn = &WN[(td * 16 + col) * 72 + q * 8];
      accN[td] = __builtin_amdgcn_mfma_f32_16x16x32_f16(a0, *(const h8*)(bn),      accN[td], 0, 0, 0);
      accN[td] = __builtin_amdgcn_mfma_f32_16x16x32_f16(a1, *(const h8*)(bn + 32), accN[td], 0, 0, 0);
      const _Float16* bh = &WHN[(td * 16 + col) * 72 + q * 8];
      accH[td] = __builtin_amdgcn_mfma_f32_16x16x32_f16(a2, *(const h8*)(bh),      accH[td], 0, 0, 0);
      accH[td] = __builtin_amdgcn_mfma_f32_16x16x32_f16(a3, *(const h8*)(bh + 32), accH[td], 0, 0, 0);
    }

#pragma unroll
    for (int reg = 0; reg < 4; reg++) {
      int lr  = 16 * wv + q * 4 + reg;
      int row = Mbase + lr;
      float rv = rLDS[lr], ovv = oLDS[lr];
#pragma unroll
      for (int td = 0; td < 4; td++) {
        int d = td * 16 + col;
        float hv = (float)ABuf[lr * 136 + 64 + d];
        float A0 = accR[td][reg] + cg2[d]       + rv * wre[d]       + ovv * wom[d];
        float A1 = accZ[td][reg] + cg2[64 + d]  + rv * wre[64 + d]  + ovv * wom[64 + d];
        float AN = accN[td][reg] + cg2[128 + d] + rv * wre[128 + d] + ovv * wom[128 + d];
        float AH = accH[td][reg] + bhn[d];
        float r  = sigmoidf_(A0);
        float z  = sigmoidf_(A1);
        float nn = tanhf_(AN + r * AH);
        float hf = (1.f - z) * nn + z * hv;
        dout[O1 + (size_t)dir * (BATCH * 64) + ((size_t)row << 6) + d] = hf;
        if (dir == 0) {
          dout[((size_t)row << 6) + d] = 0.3f * theta[((size_t)row << 6) + d] + 0.7f * hf;
        }
      }
    }
  };

  STAGE_LOAD(a, Mb0);
  STAGE_WRITE(a, Mb0);
  STAGE_LOAD(b, Mb0 + 64);            // depth-2: tile1 in flight through tile0

  __syncthreads();                    // ABuf(0) + weights visible
  compute(Mb0);
  __syncthreads();
  STAGE_WRITE(b, Mb0 + 64);
  STAGE_LOAD(a, Mb0 + 128);

  __syncthreads();
  compute(Mb0 + 64);
  __syncthreads();
  STAGE_WRITE(a, Mb0 + 128);
  STAGE_LOAD(b, Mb0 + 192);

  __syncthreads();
  compute(Mb0 + 128);
  __syncthreads();
  STAGE_WRITE(b, Mb0 + 192);

  __syncthreads();
  compute(Mb0 + 192);
#undef STAGE_LOAD
#undef STAGE_WRITE
#undef ST1
}

// ---------------------------------------------------------------- launch
extern "C" void kernel_launch(void* const* d_in, const int* in_sizes, int n_in,
                              void* d_out, int out_size, void* d_ws, size_t ws_size,
                              hipStream_t stream)
{
  const float* theta   = (const float*)d_in[0];
  const float* context = (const float*)d_in[1];
  const float* h_prev  = (const float*)d_in[2];
  const float* memory  = (const float*)d_in[3];
  const float* tw      = (const float*)d_in[4];
  const float* ipw     = (const float*)d_in[5];
  const float* ipb     = (const float*)d_in[6];
  const float* outw    = (const float*)d_in[7];
  const float* outb    = (const float*)d_in[8];
  const float* ew1     = (const float*)d_in[9];
  const float* eb1     = (const float*)d_in[10];
  const float* ew2     = (const float*)d_in[11];
  const float* eb2     = (const float*)d_in[12];
  const float* pe      = (const float*)d_in[13];
  const float* cw      = (const float*)d_in[14];
  const float* cb      = (const float*)d_in[15];
  const float* iw      = (const float*)d_in[16];
  const float* ib      = (const float*)d_in[17];
  const float* wihf    = (const float*)d_in[18];
  const float* whhf    = (const float*)d_in[19];
  const float* bihf    = (const float*)d_in[20];
  const float* bhhf    = (const float*)d_in[21];
  const float* wihr    = (const float*)d_in[22];
  const float* whhr    = (const float*)d_in[23];
  const float* bihr    = (const float*)d_in[24];
  const float* bhhr    = (const float*)d_in[25];
  const float* fw      = (const float*)d_in[26];
  const float* fb      = (const float*)d_in[27];
  const float* pi      = (const float*)d_in[28];
  float* dout = (float*)d_out;
  float* ws   = (float*)d_ws;

  bool fused = ws_size >= ((size_t)WS_E + (size_t)BATCH * 64) * sizeof(float);
  float* eout = fused ? (ws + WS_E) : (dout + O2);

  kA<<<2, 256, 0, stream>>>(memory, tw, ipw, ipb, outw, outb, wihf, bihf,
                            wihr, bihr, pe, pi, ws);
  kB1<<<1024, 256, 0, stream>>>(theta, context, cw, cb, iw, ib, pe,
                                ew1, eb1, ew2, eb2, fw, fb, dout, ws, eout);
  if (fused) {
    kC<1><<<dim3(256, 2, 1), 256, 0, stream>>>(theta, h_prev, wihf, whhf, bhhf,
                                               wihr, whhr, bhhr, ws, ws + WS_E, dout);
  } else {
    kE<<<4096, 256, 0, stream>>>(dout, ws);
    kC<0><<<dim3(256, 2, 1), 256, 0, stream>>>(theta, h_prev, wihf, whhf, bhhf,
                                               wihr, whhr, bhhr, ws, dout + O2, dout);
  }
}